// Round 1
// baseline (99.523 us; speedup 1.0000x reference)
//
#include <hip/hip_runtime.h>
#include <hip/hip_bf16.h>

typedef short s8v __attribute__((ext_vector_type(8)));
typedef float f4v __attribute__((ext_vector_type(4)));
typedef unsigned short u16;
typedef unsigned int   u32;

#define NHEAD 8
#define FDIM  32   // D/2

__device__ __forceinline__ float bf2f(u16 b) {
    return __uint_as_float(((u32)b) << 16);
}
__device__ __forceinline__ u16 f2bf(float f) {
    u32 u = __float_as_uint(f);
    u32 r = u + 0x7fffu + ((u >> 16) & 1u);   // round-to-nearest-even
    return (u16)(r >> 16);
}

// flags: [0]=floats-are-bf16, [1]=mask-is-byte, [2]=indices-are-int64
__global__ void detect_kernel(const u32* w1, const u32* mk, const u32* ei, int* flags) {
    if (threadIdx.x == 0 && blockIdx.x == 0) {
        // W1 ~ N(0, 1/8). If bf16: bits 7..14 of each u32 word are the low element's
        // exponent byte, concentrated in [0x70,0x7F]. If fp32: those are uniform mantissa bits.
        int cnt = 0;
        for (int i = 0; i < 64; ++i) {
            u32 e = (w1[i] >> 7) & 0xFFu;
            if (e >= 0x70u && e <= 0x7Fu) ++cnt;
        }
        int big = 0;
        for (int i = 0; i < 64; ++i) if (mk[i] > 1u) big = 1;      // packed bytes -> words > 1
        int oddnz = 0;
        for (int i = 0; i < 64; ++i) if (ei[2 * i + 1] != 0u) oddnz = 1; // int64 -> odd words all 0
        flags[0] = (cnt > 32) ? 1 : 0;
        flags[1] = big;
        flags[2] = oddnz ? 0 : 1;
        flags[3] = 0;
    }
}

__global__ __launch_bounds__(256)
void attn_scatter_kernel(const void* __restrict__ a_ij,
                         const void* __restrict__ pos,
                         const void* __restrict__ eidx,
                         const void* __restrict__ maskp,
                         const int*  __restrict__ proP,
                         const void* __restrict__ W1p,
                         const void* __restrict__ b1p,
                         const void* __restrict__ W2p,
                         const void* __restrict__ b2p,
                         const void* __restrict__ Whp,
                         float* __restrict__ agg,
                         const int* __restrict__ flags,
                         int E, int ntiles, int tpw)
{
    const int isbf  = flags[0];
    const int mbyte = flags[1];
    const int i64   = flags[2];
    const int pro   = proP[0];

    const int lane  = threadIdx.x & 63;
    const int gwave = blockIdx.x * (blockDim.x >> 6) + (threadIdx.x >> 6);
    int t0 = gwave * tpw;
    if (t0 >= ntiles) return;
    int tend = t0 + tpw; if (tend > ntiles) tend = ntiles;

    const int c0 = lane & 15, c1 = c0 + 16;
    const int krow = (lane >> 4) * 8;

    // ---- per-wave parameter setup ----
    float WhV[NHEAD]; float sumWh = 0.f;
    float b1c0, b1c1, w2c0, w2c1, b2v;
    s8v bfrag[2][2];   // [col-block][k-half]
    if (isbf) {
        const u16* w1 = (const u16*)W1p; const u16* b1 = (const u16*)b1p;
        const u16* w2 = (const u16*)W2p; const u16* b2 = (const u16*)b2p;
        const u16* wh = (const u16*)Whp;
        #pragma unroll
        for (int h = 0; h < NHEAD; ++h) { WhV[h] = bf2f(wh[h]); sumWh += WhV[h]; }
        b2v = bf2f(b2[0]);
        b1c0 = bf2f(b1[c0]); b1c1 = bf2f(b1[c1]);
        w2c0 = bf2f(w2[c0]); w2c1 = bf2f(w2[c1]);
        #pragma unroll
        for (int cb = 0; cb < 2; ++cb)
            #pragma unroll
            for (int kh = 0; kh < 2; ++kh)
                #pragma unroll
                for (int j = 0; j < 8; ++j) {
                    int k = kh * 32 + krow + j;
                    bfrag[cb][kh][j] = (short)w1[k * FDIM + cb * 16 + c0];
                }
    } else {
        const float* w1 = (const float*)W1p; const float* b1 = (const float*)b1p;
        const float* w2 = (const float*)W2p; const float* b2 = (const float*)b2p;
        const float* wh = (const float*)Whp;
        #pragma unroll
        for (int h = 0; h < NHEAD; ++h) { WhV[h] = wh[h]; sumWh += WhV[h]; }
        b2v = b2[0];
        b1c0 = b1[c0]; b1c1 = b1[c1];
        w2c0 = w2[c0]; w2c1 = w2[c1];
        #pragma unroll
        for (int cb = 0; cb < 2; ++cb)
            #pragma unroll
            for (int kh = 0; kh < 2; ++kh)
                #pragma unroll
                for (int j = 0; j < 8; ++j) {
                    int k = kh * 32 + krow + j;
                    bfrag[cb][kh][j] = (short)f2bf(w1[k * FDIM + cb * 16 + c0]);
                }
    }

    const u16*   a16 = (const u16*)a_ij;
    const float* a32 = (const float*)a_ij;
    const int*   e32 = (const int*)eidx;
    const long long* e64 = (const long long*)eidx;
    const unsigned char* m8 = (const unsigned char*)maskp;
    const int*   m32 = (const int*)maskp;

    const int hi4 = (lane >> 4) & 1;           // which Wh half this lane's rows use
    const int myedge = (lane >> 3) & 1;        // rows 0-7 -> edge0, 8-15 -> edge1

    for (int t = t0; t < tend; ++t) {
        const int e0 = t * 2;
        const bool has1 = (e0 + 1) < E;
        int src0 = i64 ? (int)e64[e0] : e32[e0];
        int src1 = has1 ? (i64 ? (int)e64[e0 + 1] : e32[e0 + 1]) : 0;
        int mk0  = mbyte ? (int)m8[e0] : m32[e0];
        int mk1  = has1 ? (mbyte ? (int)m8[e0 + 1] : m32[e0 + 1]) : 1;
        bool v0 = (src0 >= pro) && (mk0 == 0);
        bool v1 = has1 && (src1 >= pro) && (mk1 == 0);
        if (!v0 && !v1) continue;

        const bool lv = myedge ? v1 : v0;
        s8v a0 = {0,0,0,0,0,0,0,0};
        s8v a1 = {0,0,0,0,0,0,0,0};
        const size_t rowbase = ((size_t)e0 * 8 + (size_t)(lane & 15)) * 64 + (size_t)krow;
        if (lv) {
            if (isbf) {
                a0 = *(const s8v*)(a16 + rowbase);
                a1 = *(const s8v*)(a16 + rowbase + 32);
            } else {
                const float* p = a32 + rowbase;
                #pragma unroll
                for (int j = 0; j < 8; ++j) a0[j] = (short)f2bf(p[j]);
                #pragma unroll
                for (int j = 0; j < 8; ++j) a1[j] = (short)f2bf(p[32 + j]);
            }
        }

        f4v C0 = {0.f,0.f,0.f,0.f}, C1 = {0.f,0.f,0.f,0.f};
        C0 = __builtin_amdgcn_mfma_f32_16x16x32_bf16(a0, bfrag[0][0], C0, 0, 0, 0);
        C0 = __builtin_amdgcn_mfma_f32_16x16x32_bf16(a1, bfrag[0][1], C0, 0, 0, 0);
        C1 = __builtin_amdgcn_mfma_f32_16x16x32_bf16(a0, bfrag[1][0], C1, 0, 0, 0);
        C1 = __builtin_amdgcn_mfma_f32_16x16x32_bf16(a1, bfrag[1][1], C1, 0, 0, 0);

        // epilogue: bias + leaky_relu + W2 + Wh, reduce 32 cols x (16 lanes) -> per-edge att
        float partial = 0.f;
        #pragma unroll
        for (int i = 0; i < 4; ++i) {
            float x0 = C0[i] + b1c0; x0 = (x0 >= 0.f) ? x0 : 0.01f * x0;
            float x1 = C1[i] + b1c1; x1 = (x1 >= 0.f) ? x1 : 0.01f * x1;
            float trow = x0 * w2c0 + x1 * w2c1;
            float whv = hi4 ? WhV[i + 4] : WhV[i];
            partial += trow * whv;
        }
        partial += __shfl_xor(partial, 1);
        partial += __shfl_xor(partial, 2);
        partial += __shfl_xor(partial, 4);
        partial += __shfl_xor(partial, 8);
        partial += __shfl_xor(partial, 16);
        // lanes 0..31 hold edge0 pre-att, lanes 32..63 hold edge1 pre-att
        float att = partial + b2v * sumWh;

        if ((lane & 31) == 0) {
            const int which = lane >> 5;
            const bool vv = which ? v1 : v0;
            if (vv) {
                const int s = which ? src1 : src0;
                const int e = e0 + which;
                const int d = i64 ? (int)e64[E + e] : e32[E + e];
                float px, py, pz, qx, qy, qz;
                if (isbf) {
                    const u16* pp = (const u16*)pos;
                    px = bf2f(pp[3 * s]); py = bf2f(pp[3 * s + 1]); pz = bf2f(pp[3 * s + 2]);
                    qx = bf2f(pp[3 * d]); qy = bf2f(pp[3 * d + 1]); qz = bf2f(pp[3 * d + 2]);
                } else {
                    const float* pp = (const float*)pos;
                    px = pp[3 * s]; py = pp[3 * s + 1]; pz = pp[3 * s + 2];
                    qx = pp[3 * d]; qy = pp[3 * d + 1]; qz = pp[3 * d + 2];
                }
                float dx = px - qx, dy = py - qy, dz = pz - qz;
                float nrm = sqrtf(dx * dx + dy * dy + dz * dz) + 1e-6f;
                float sc = att / nrm;
                atomicAdd(&agg[3 * s + 0], dx * sc);
                atomicAdd(&agg[3 * s + 1], dy * sc);
                atomicAdd(&agg[3 * s + 2], dz * sc);
            }
        }
    }
}

__global__ void finalize_kernel(const void* __restrict__ pos,
                                const void* __restrict__ gidxp,
                                const float* __restrict__ agg,
                                void* __restrict__ outp,
                                const int* __restrict__ flags, int G)
{
    int g = blockIdx.x * blockDim.x + threadIdx.x;
    if (g >= G) return;
    const int isbf = flags[0], i64 = flags[2];
    const int idx = i64 ? (int)((const long long*)gidxp)[g] : ((const int*)gidxp)[g];
    #pragma unroll
    for (int c = 0; c < 3; ++c) {
        float p;
        if (isbf) p = bf2f(((const u16*)pos)[3 * idx + c]);
        else      p = ((const float*)pos)[3 * idx + c];
        float v = p + agg[3 * idx + c];
        if (isbf) ((u16*)outp)[3 * g + c] = f2bf(v);
        else      ((float*)outp)[3 * g + c] = v;
    }
}

extern "C" void kernel_launch(void* const* d_in, const int* in_sizes, int n_in,
                              void* d_out, int out_size, void* d_ws, size_t ws_size,
                              hipStream_t stream) {
    const void* a_ij = d_in[0];
    const void* pos  = d_in[1];
    // d_in[2] generate_node_dist: unused
    const void* eidx = d_in[3];
    // d_in[4] parent_node_idxes: unused
    const void* gidx = d_in[5];
    const void* mask = d_in[6];
    const int*  pro  = (const int*)d_in[7];   // low 32 bits valid for int32 or int64 LE
    const void* W1   = d_in[8];
    const void* b1   = d_in[9];
    const void* W2   = d_in[10];
    const void* b2   = d_in[11];
    const void* Wh   = d_in[12];

    const int E = in_sizes[3] / 2;
    const int N = in_sizes[1] / 3;
    const int G = in_sizes[5];

    const size_t aggBytes = (size_t)N * 3 * sizeof(float);
    float* agg = (float*)d_ws;
    int* flags = (int*)((char*)d_ws + ((aggBytes + 63) & ~(size_t)63));

    detect_kernel<<<1, 64, 0, stream>>>((const u32*)W1, (const u32*)mask, (const u32*)eidx, flags);
    hipMemsetAsync(agg, 0, aggBytes, stream);

    const int ntiles = (E + 1) / 2;
    const int tpw = 8;
    const int nwaves = (ntiles + tpw - 1) / tpw;
    const int nblocks = (nwaves + 3) / 4;
    attn_scatter_kernel<<<nblocks, 256, 0, stream>>>(a_ij, pos, eidx, mask, pro,
                                                     W1, b1, W2, b2, Wh,
                                                     agg, flags, E, ntiles, tpw);

    finalize_kernel<<<(G + 255) / 256, 256, 0, stream>>>(pos, gidx, agg, d_out, flags, G);
}